// Round 7
// baseline (72.908 us; speedup 1.0000x reference)
//
#include <hip/hip_runtime.h>

// B=8, H=W=256, single channel. Output: one fp32 scalar (composite loss).
#define HW_ELEMS 65536
#define BIGD 1e4f
#define EPSL 1e-8f
#define NBLK 2048   // one block per (b, y) row

__device__ __forceinline__ float waveSum(float v) {
  #pragma unroll
  for (int off = 32; off > 0; off >>= 1) v += __shfl_down(v, off);
  return v;
}

// partial layout (SoA): partial[q*NBLK + blk], q:
//   0 = inter (sum p*t), 1 = sum_p, 2 = sum_t, 3 = attn sse, 4 = boundary (ungated)
// No atomics: each block writes its own 5 slots; 1-block finalize reduces.
//
// Exact EDT, latency-optimized: radii 1..8 are probed UNCONDITIONALLY with all
// loads issued before any use (one memory round-trip); the early-exit tail
// loop handles the ~1e-5 of columns/rows not resolved within radius 8, so the
// result is still the exact min over the full 256 range.
__global__ __launch_bounds__(256) void fused_kernel(
    const float* __restrict__ probs, const int* __restrict__ targets,
    const float* __restrict__ attn, float* __restrict__ partial) {
  const int blk = blockIdx.x;
  const int b = blk >> 8;
  const int y = blk & 255;
  const int x = threadIdx.x;
  const int* __restrict__ timg = targets + b * HW_ELEMS;

  const int rowoff = b * HW_ELEMS + y * 256 + x;
  const float p = probs[rowoff];   // issued early; latency hides under phase 1
  const float a = attn[rowoff];
  const int t0 = timg[y * 256 + x];
  const float tf = (float)t0;

  // ---- phase 1: column distances, r=1..8 unconditional ----
  int tu[8], td[8];
  #pragma unroll
  for (int j = 0; j < 8; ++j) {
    const int yu = y - 1 - j, yd = y + 1 + j;
    tu[j] = (yu >= 0)  ? timg[yu * 256 + x] : -1;   // -1 = out of bounds
    td[j] = (yd < 256) ? timg[yd * 256 + x] : -1;
  }
  float dpos = t0 ? 0.f : BIGD;   // nearest fg in column x
  float dneg = t0 ? BIGD : 0.f;   // nearest bg in column x
  #pragma unroll
  for (int j = 0; j < 8; ++j) {
    const float fr = (float)(1 + j);
    if (tu[j] == 1) dpos = fminf(dpos, fr); else if (tu[j] == 0) dneg = fminf(dneg, fr);
    if (td[j] == 1) dpos = fminf(dpos, fr); else if (td[j] == 0) dneg = fminf(dneg, fr);
  }
  // rare tail (unresolved beyond radius 8): exact outward search continues
  for (int r = 9; r < 256; r += 4) {
    if (dpos < BIGD && dneg < BIGD) break;
    int su[4], sd[4];
    #pragma unroll
    for (int j = 0; j < 4; ++j) {
      const int yu = y - (r + j), yd = y + (r + j);
      su[j] = (yu >= 0)  ? timg[yu * 256 + x] : -1;
      sd[j] = (yd < 256) ? timg[yd * 256 + x] : -1;
    }
    #pragma unroll
    for (int j = 0; j < 4; ++j) {
      const float fr = (float)(r + j);
      if (su[j] == 1) dpos = fminf(dpos, fr); else if (su[j] == 0) dneg = fminf(dneg, fr);
      if (sd[j] == 1) dpos = fminf(dpos, fr); else if (sd[j] == 0) dneg = fminf(dneg, fr);
    }
  }

  __shared__ float g2p[256], g2n[256];
  g2p[x] = dpos * dpos;
  g2n[x] = dneg * dneg;
  __syncthreads();

  // ---- phase 2: row lower envelope, r=1..8 unconditional ----
  float m2p = g2p[x], m2n = g2n[x];
  {
    float lp[8], ln[8], rp[8], rn[8];
    #pragma unroll
    for (int j = 0; j < 8; ++j) {
      const int xl = x - 1 - j, xr = x + 1 + j;
      lp[j] = (xl >= 0)  ? g2p[xl] : 3.4e37f;
      ln[j] = (xl >= 0)  ? g2n[xl] : 3.4e37f;
      rp[j] = (xr < 256) ? g2p[xr] : 3.4e37f;
      rn[j] = (xr < 256) ? g2n[xr] : 3.4e37f;
    }
    #pragma unroll
    for (int j = 0; j < 8; ++j) {
      const float rr = (float)((1 + j) * (1 + j));
      m2p = fminf(m2p, rr + lp[j]); m2p = fminf(m2p, rr + rp[j]);
      m2n = fminf(m2n, rr + ln[j]); m2n = fminf(m2n, rr + rn[j]);
    }
  }
  // rare tail: only needed if some g^2 beyond radius 8 could still win
  for (int r = 9; r < 256; r += 4) {
    const float rr0 = (float)(r * r);
    if (rr0 >= m2p && rr0 >= m2n) break;
    #pragma unroll
    for (int j = 0; j < 4; ++j) {
      const int rj = r + j;
      const float rr = (float)(rj * rj);
      const int xl = x - rj, xr = x + rj;
      if (xl >= 0)  { m2p = fminf(m2p, rr + g2p[xl]); m2n = fminf(m2n, rr + g2n[xl]); }
      if (xr < 256) { m2p = fminf(m2p, rr + g2p[xr]); m2n = fminf(m2n, rr + g2n[xr]); }
    }
  }

  const float sdt = sqrtf(m2p) + sqrtf(m2n);
  const float contrib = p * sdt;           // any_fg gate applied in finalize
  const float d = a - tf;

  // ---- fused row reductions ----
  const float v0 = waveSum(p * tf);
  const float v1 = waveSum(p);
  const float v2 = waveSum(tf);
  const float v3 = waveSum(d * d);
  const float v4 = waveSum(contrib);

  __shared__ float lds[4][5];
  const int wid = threadIdx.x >> 6, lane = threadIdx.x & 63;
  if (lane == 0) {
    lds[wid][0] = v0; lds[wid][1] = v1; lds[wid][2] = v2;
    lds[wid][3] = v3; lds[wid][4] = v4;
  }
  __syncthreads();
  if (threadIdx.x == 0) {
    float s[5] = {0.f, 0.f, 0.f, 0.f, 0.f};
    #pragma unroll
    for (int w = 0; w < 4; ++w)
      #pragma unroll
      for (int q = 0; q < 5; ++q) s[q] += lds[w][q];
    #pragma unroll
    for (int q = 0; q < 5; ++q) partial[q * NBLK + blk] = s[q];  // plain stores
  }
}

// Single block, 256 threads: reduce 5*2048 partials, apply loss formula.
__global__ __launch_bounds__(256) void finalize_kernel(
    const float* __restrict__ partial, float* __restrict__ out) {
  const int tid = threadIdx.x;
  __shared__ float red[32][8];   // [qsel*8 + b][sub]
  __shared__ float sred[4];

  const int pair = tid >> 3, sub = tid & 7;     // 32 pairs x 8 subs
  const int qsel = pair >> 3;                    // 0..3
  const int bb = pair & 7;
  const int qoff[4] = {0, 1, 2, 4};
  const int base = qoff[qsel] * NBLK + bb * 256 + sub * 32;
  float s = 0.f;
  #pragma unroll
  for (int j = 0; j < 32; ++j) s += partial[base + j];
  red[pair][sub] = s;

  // global sse (q=3): 256 threads x 8 entries
  float e = 0.f;
  #pragma unroll
  for (int j = 0; j < 8; ++j) e += partial[3 * NBLK + tid * 8 + j];
  e = waveSum(e);
  if ((tid & 63) == 0) sred[tid >> 6] = e;
  __syncthreads();

  if (tid == 0) {
    float dsum = 0.f, tsum = 0.f, bsum = 0.f;
    for (int b2 = 0; b2 < 8; ++b2) {
      float inter = 0.f, sp = 0.f, st = 0.f, bd = 0.f;
      #pragma unroll
      for (int k = 0; k < 8; ++k) {
        inter += red[0 * 8 + b2][k];
        sp    += red[1 * 8 + b2][k];
        st    += red[2 * 8 + b2][k];
        bd    += red[3 * 8 + b2][k];
      }
      dsum += (2.f * inter + EPSL) / (sp + st + EPSL);
      const float fn = st - inter;
      const float fp = sp - inter;
      tsum += (inter + EPSL) / (inter + 0.3f * fn + 0.7f * fp + EPSL);
      bsum += (st > 0.5f) ? bd : 0.f;   // any_fg gate
    }
    const float sse = sred[0] + sred[1] + sred[2] + sred[3];
    const float dl = 1.f - dsum * 0.125f;
    const float tl = 1.f - tsum * 0.125f;
    const float bl = bsum * (1.f / 524288.f);
    const float al = sse * (1.f / 524288.f);
    out[0] = 1.0f * dl + 0.7f * tl + 0.5f * bl + 0.3f * al;
  }
}

extern "C" void kernel_launch(void* const* d_in, const int* in_sizes, int n_in,
                              void* d_out, int out_size, void* d_ws, size_t ws_size,
                              hipStream_t stream) {
  const float* probs   = (const float*)d_in[0];
  const int*   targets = (const int*)d_in[1];
  const float* attn    = (const float*)d_in[2];
  float* out = (float*)d_out;
  float* partial = (float*)d_ws;  // 5 * 2048 floats = 40 KB; fully written each call
  fused_kernel<<<NBLK, 256, 0, stream>>>(probs, targets, attn, partial);
  finalize_kernel<<<1, 256, 0, stream>>>(partial, out);
}